// Round 4
// baseline (363.111 us; speedup 1.0000x reference)
//
#include <hip/hip_runtime.h>

// GCN: x1 = relu(Agg(x@W1)+b1); x2 = relu(Agg(x1@W2)+b2); out = [x1,x2]@linW + linb
// Agg(h)[i] = dinv[i]^2*h[i] + sum_{e: dst=i} dinv[src]*dinv[i]*h[src]
// CSR by dst (counting sort) -> per-node wave gather-reduce. n=50000, D=128, E=800000.

#define D128 128

// ---------- degree count ----------
__global__ void k_count(const int* __restrict__ dst, int* __restrict__ indeg, int E) {
    int e = blockIdx.x * 256 + threadIdx.x;
    if (e < E) atomicAdd(&indeg[dst[e]], 1);
}

// ---------- scan (exclusive) over indeg -> row_ptr ; fused dinv ----------
__global__ void k_scan1(const int* __restrict__ indeg, int* __restrict__ row_ptr,
                        int* __restrict__ bsum, float* __restrict__ dinv, int n) {
    __shared__ int tmp[256];
    int i = blockIdx.x * 256 + threadIdx.x;
    int v = (i < n) ? indeg[i] : 0;
    if (i < n) dinv[i] = rsqrtf((float)(v + 1));  // +1 self loop
    tmp[threadIdx.x] = v;
    __syncthreads();
    for (int off = 1; off < 256; off <<= 1) {
        int t = (threadIdx.x >= off) ? tmp[threadIdx.x - off] : 0;
        __syncthreads();
        tmp[threadIdx.x] += t;
        __syncthreads();
    }
    if (i < n) row_ptr[i] = tmp[threadIdx.x] - v;
    if (threadIdx.x == 255) bsum[blockIdx.x] = tmp[255];
}

__global__ void k_scan2(int* __restrict__ bsum, int nb) {  // one block, nb<=256
    __shared__ int tmp[256];
    int v = (threadIdx.x < nb) ? bsum[threadIdx.x] : 0;
    tmp[threadIdx.x] = v;
    __syncthreads();
    for (int off = 1; off < 256; off <<= 1) {
        int t = (threadIdx.x >= off) ? tmp[threadIdx.x - off] : 0;
        __syncthreads();
        tmp[threadIdx.x] += t;
        __syncthreads();
    }
    if (threadIdx.x < nb) bsum[threadIdx.x] = tmp[threadIdx.x] - v;
}

__global__ void k_scan3(int* __restrict__ row_ptr, const int* __restrict__ bsum,
                        int* __restrict__ cursor, int n, int E) {
    int i = blockIdx.x * 256 + threadIdx.x;
    if (i < n) {
        int r = row_ptr[i] + bsum[blockIdx.x];
        row_ptr[i] = r;
        cursor[i] = r;
    }
    if (blockIdx.x == 0 && threadIdx.x == 0) row_ptr[n] = E;
}

// ---------- CSR fill: packed (src_bits, norm) ----------
__global__ void k_fill(const int* __restrict__ src, const int* __restrict__ dst,
                       const float* __restrict__ dinv, int* __restrict__ cursor,
                       float2* __restrict__ csr, int E) {
    int e = blockIdx.x * 256 + threadIdx.x;
    if (e >= E) return;
    int s = src[e], d = dst[e];
    int pos = atomicAdd(&cursor[d], 1);
    csr[pos] = make_float2(__int_as_float(s), dinv[s] * dinv[d]);
}

// ---------- fused aggregate + bias + relu ----------
// 1 wave per node, float2 per lane; 8 gathers in flight.
__global__ __launch_bounds__(256) void k_agg_csr(
    const float* __restrict__ h, const int* __restrict__ row_ptr,
    const float2* __restrict__ csr, const float* __restrict__ dinv,
    const float* __restrict__ bias, float* __restrict__ o, int n)
{
    int node = blockIdx.x * 4 + (threadIdx.x >> 6);
    int lane = threadIdx.x & 63;
    if (node >= n) return;
    const float2* h2 = (const float2*)h;
    float dv = dinv[node];
    float2 hv = h2[node * 64 + lane];
    float ax = dv * dv * hv.x, ay = dv * dv * hv.y;
    int j = row_ptr[node], end = row_ptr[node + 1];
    for (; j + 7 < end; j += 8) {
        float2 c0 = csr[j+0], c1 = csr[j+1], c2 = csr[j+2], c3 = csr[j+3];
        float2 c4 = csr[j+4], c5 = csr[j+5], c6 = csr[j+6], c7 = csr[j+7];
        float2 v0 = h2[__float_as_int(c0.x) * 64 + lane];
        float2 v1 = h2[__float_as_int(c1.x) * 64 + lane];
        float2 v2 = h2[__float_as_int(c2.x) * 64 + lane];
        float2 v3 = h2[__float_as_int(c3.x) * 64 + lane];
        float2 v4 = h2[__float_as_int(c4.x) * 64 + lane];
        float2 v5 = h2[__float_as_int(c5.x) * 64 + lane];
        float2 v6 = h2[__float_as_int(c6.x) * 64 + lane];
        float2 v7 = h2[__float_as_int(c7.x) * 64 + lane];
        ax += c0.y*v0.x + c1.y*v1.x + c2.y*v2.x + c3.y*v3.x
            + c4.y*v4.x + c5.y*v5.x + c6.y*v6.x + c7.y*v7.x;
        ay += c0.y*v0.y + c1.y*v1.y + c2.y*v2.y + c3.y*v3.y
            + c4.y*v4.y + c5.y*v5.y + c6.y*v6.y + c7.y*v7.y;
    }
    for (; j + 3 < end; j += 4) {
        float2 c0 = csr[j+0], c1 = csr[j+1], c2 = csr[j+2], c3 = csr[j+3];
        float2 v0 = h2[__float_as_int(c0.x) * 64 + lane];
        float2 v1 = h2[__float_as_int(c1.x) * 64 + lane];
        float2 v2 = h2[__float_as_int(c2.x) * 64 + lane];
        float2 v3 = h2[__float_as_int(c3.x) * 64 + lane];
        ax += c0.y*v0.x + c1.y*v1.x + c2.y*v2.x + c3.y*v3.x;
        ay += c0.y*v0.y + c1.y*v1.y + c2.y*v2.y + c3.y*v3.y;
    }
    for (; j < end; ++j) {
        float2 c = csr[j];
        float2 v = h2[__float_as_int(c.x) * 64 + lane];
        ax += c.y * v.x;
        ay += c.y * v.y;
    }
    float2 bv = ((const float2*)bias)[lane];
    float2 ov = {fmaxf(ax + bv.x, 0.f), fmaxf(ay + bv.y, 0.f)};
    ((float2*)o)[node * 64 + lane] = ov;
}

// ---------- dense GEMM: C[32 x 128] = A@W, K=128; thread = 2 rows x 8 cols ----------
#define AS_STRIDE 132  // 128 + 4 pad: breaks bank aliasing, keeps 16B alignment

__global__ __launch_bounds__(256) void k_gemm(
    const float* __restrict__ A, const float* __restrict__ W,
    float* __restrict__ C, int n)
{
    __shared__ float Wc[64 * 128];        // 32 KB (K-chunk)
    __shared__ float As[32 * AS_STRIDE];  // 16.5 KB
    int tid = threadIdx.x;
    int row0 = blockIdx.x * 32;

    {   // stage A tile (zero-fill OOB rows), padded-transposed-free layout
        const float4* A4 = (const float4*)(A + (size_t)row0 * D128);
#pragma unroll
        for (int it = 0; it < 4; ++it) {
            int f = it * 256 + tid;        // float4 index in 32x128 tile
            int r = f >> 5, c4 = f & 31;
            float4 v = {0.f, 0.f, 0.f, 0.f};
            if (row0 + r < n) v = A4[f];
            *(float4*)&As[r * AS_STRIDE + c4 * 4] = v;
        }
    }

    int cg = tid & 15;   // cols cg*8 .. cg*8+7
    int rg = tid >> 4;   // rows rg*2, rg*2+1
    float4 acc[2][2] = {{{0,0,0,0},{0,0,0,0}},{{0,0,0,0},{0,0,0,0}}};
    const float* a0p = &As[(rg * 2) * AS_STRIDE];
    const float* a1p = &As[(rg * 2 + 1) * AS_STRIDE];

    for (int kb = 0; kb < 2; ++kb) {
        if (kb) __syncthreads();
        const float4* W4 = (const float4*)(W + kb * 64 * D128);
        float4* Wc4 = (float4*)Wc;
#pragma unroll
        for (int it = 0; it < 8; ++it)
            Wc4[it * 256 + tid] = W4[it * 256 + tid];
        __syncthreads();

#pragma unroll 4
        for (int k = 0; k < 64; ++k) {
            float4 w0 = *(const float4*)&Wc[k * D128 + cg * 8];
            float4 w1 = *(const float4*)&Wc[k * D128 + cg * 8 + 4];
            float a0 = a0p[kb * 64 + k];
            float a1 = a1p[kb * 64 + k];
            acc[0][0].x += a0*w0.x; acc[0][0].y += a0*w0.y; acc[0][0].z += a0*w0.z; acc[0][0].w += a0*w0.w;
            acc[0][1].x += a0*w1.x; acc[0][1].y += a0*w1.y; acc[0][1].z += a0*w1.z; acc[0][1].w += a0*w1.w;
            acc[1][0].x += a1*w0.x; acc[1][0].y += a1*w0.y; acc[1][0].z += a1*w0.z; acc[1][0].w += a1*w0.w;
            acc[1][1].x += a1*w1.x; acc[1][1].y += a1*w1.y; acc[1][1].z += a1*w1.z; acc[1][1].w += a1*w1.w;
        }
    }

#pragma unroll
    for (int r = 0; r < 2; ++r) {
        int row = row0 + rg * 2 + r;
        if (row < n) {
            float4* Cp = (float4*)&C[(size_t)row * D128 + cg * 8];
            Cp[0] = acc[r][0];
            Cp[1] = acc[r][1];
        }
    }
}

// ---------- final: out = [x1,x2] @ linW + linb  (K=256 in 4 chunks) ----------
__global__ __launch_bounds__(256) void k_gemm_cat(
    const float* __restrict__ A0, const float* __restrict__ A1,
    const float* __restrict__ W, const float* __restrict__ bias,
    float* __restrict__ C, int n)
{
    __shared__ float Wc[64 * 128];           // 32 KB
    __shared__ float As[2][32 * AS_STRIDE];  // 33 KB
    int tid = threadIdx.x;
    int row0 = blockIdx.x * 32;

    {
        const float4* A4a = (const float4*)(A0 + (size_t)row0 * D128);
        const float4* A4b = (const float4*)(A1 + (size_t)row0 * D128);
#pragma unroll
        for (int it = 0; it < 4; ++it) {
            int f = it * 256 + tid;
            int r = f >> 5, c4 = f & 31;
            float4 va = {0.f,0.f,0.f,0.f}, vb = {0.f,0.f,0.f,0.f};
            if (row0 + r < n) { va = A4a[f]; vb = A4b[f]; }
            *(float4*)&As[0][r * AS_STRIDE + c4 * 4] = va;
            *(float4*)&As[1][r * AS_STRIDE + c4 * 4] = vb;
        }
    }

    int cg = tid & 15;
    int rg = tid >> 4;
    float4 acc[2][2] = {{{0,0,0,0},{0,0,0,0}},{{0,0,0,0},{0,0,0,0}}};

    for (int ch = 0; ch < 4; ++ch) {
        if (ch) __syncthreads();
        const float4* W4 = (const float4*)(W + ch * 64 * D128);
        float4* Wc4 = (float4*)Wc;
#pragma unroll
        for (int it = 0; it < 8; ++it)
            Wc4[it * 256 + tid] = W4[it * 256 + tid];
        __syncthreads();

        const float* a0p = &As[ch >> 1][(rg * 2) * AS_STRIDE] + (ch & 1) * 64;
        const float* a1p = &As[ch >> 1][(rg * 2 + 1) * AS_STRIDE] + (ch & 1) * 64;
#pragma unroll 4
        for (int k = 0; k < 64; ++k) {
            float4 w0 = *(const float4*)&Wc[k * D128 + cg * 8];
            float4 w1 = *(const float4*)&Wc[k * D128 + cg * 8 + 4];
            float a0 = a0p[k];
            float a1 = a1p[k];
            acc[0][0].x += a0*w0.x; acc[0][0].y += a0*w0.y; acc[0][0].z += a0*w0.z; acc[0][0].w += a0*w0.w;
            acc[0][1].x += a0*w1.x; acc[0][1].y += a0*w1.y; acc[0][1].z += a0*w1.z; acc[0][1].w += a0*w1.w;
            acc[1][0].x += a1*w0.x; acc[1][0].y += a1*w0.y; acc[1][0].z += a1*w0.z; acc[1][0].w += a1*w0.w;
            acc[1][1].x += a1*w1.x; acc[1][1].y += a1*w1.y; acc[1][1].z += a1*w1.z; acc[1][1].w += a1*w1.w;
        }
    }

    float4 bv0 = ((const float4*)bias)[cg * 2];
    float4 bv1 = ((const float4*)bias)[cg * 2 + 1];
#pragma unroll
    for (int r = 0; r < 2; ++r) {
        int row = row0 + rg * 2 + r;
        if (row < n) {
            float4* Cp = (float4*)&C[(size_t)row * D128 + cg * 8];
            float4 v0 = acc[r][0], v1 = acc[r][1];
            v0.x += bv0.x; v0.y += bv0.y; v0.z += bv0.z; v0.w += bv0.w;
            v1.x += bv1.x; v1.y += bv1.y; v1.z += bv1.z; v1.w += bv1.w;
            Cp[0] = v0;
            Cp[1] = v1;
        }
    }
}

extern "C" void kernel_launch(void* const* d_in, const int* in_sizes, int n_in,
                              void* d_out, int out_size, void* d_ws, size_t ws_size,
                              hipStream_t stream) {
    const float* x    = (const float*)d_in[0];
    const int*   ei   = (const int*)d_in[1];
    const float* W1   = (const float*)d_in[2];
    const float* b1   = (const float*)d_in[3];
    const float* W2   = (const float*)d_in[4];
    const float* b2   = (const float*)d_in[5];
    const float* linW = (const float*)d_in[6];
    const float* linb = (const float*)d_in[7];

    int n = in_sizes[0] / D128;
    int E = in_sizes[1] / 2;
    const int* src = ei;
    const int* dst = ei + E;

    float* out = (float*)d_out;
    float* ws  = (float*)d_ws;

    // ws layout (floats): csr[2E] | indeg[n] | dinv[n] | row_ptr[n+1] | bsum[256]
    //                     | cursor[n] | (align16) | x1[n*128] | x2[n*128]
    size_t o = 0;
    float2* csr   = (float2*)(ws + o);  o += 2 * (size_t)E;
    int*   indeg  = (int*)(ws + o);     o += n;
    float* dinv   = ws + o;             o += n;
    int*   row_ptr= (int*)(ws + o);     o += n + 1;
    int*   bsum   = (int*)(ws + o);     o += 256;
    int*   cursor = (int*)(ws + o);     o += n;
    o = (o + 3) & ~(size_t)3;
    float* x1     = ws + o;             o += (size_t)n * D128;
    float* x2     = ws + o;
    float* h      = out;  // reuse output buffer as GEMM scratch

    int gn = (n + 255) / 256;
    int gE = (E + 255) / 256;
    int gemmBlocks = (n + 31) / 32;
    int aggBlocks  = (n + 3) / 4;

    // CSR build
    hipMemsetAsync(indeg, 0, (size_t)n * sizeof(int), stream);
    k_count<<<gE, 256, 0, stream>>>(dst, indeg, E);
    k_scan1<<<gn, 256, 0, stream>>>(indeg, row_ptr, bsum, dinv, n);
    k_scan2<<<1, 256, 0, stream>>>(bsum, gn);
    k_scan3<<<gn, 256, 0, stream>>>(row_ptr, bsum, cursor, n, E);
    k_fill<<<gE, 256, 0, stream>>>(src, dst, dinv, cursor, csr, E);

    // layer 1
    k_gemm<<<gemmBlocks, 256, 0, stream>>>(x, W1, h, n);
    k_agg_csr<<<aggBlocks, 256, 0, stream>>>(h, row_ptr, csr, dinv, b1, x1, n);

    // layer 2
    k_gemm<<<gemmBlocks, 256, 0, stream>>>(x1, W2, h, n);
    k_agg_csr<<<aggBlocks, 256, 0, stream>>>(h, row_ptr, csr, dinv, b2, x2, n);

    // final
    k_gemm_cat<<<gemmBlocks, 256, 0, stream>>>(x1, x2, linW, linb, out, n);
}

// Round 6
// 356.669 us; speedup vs baseline: 1.0181x; 1.0181x over previous
//
#include <hip/hip_runtime.h>

// GCN: x1 = relu(Agg(x@W1)+b1); x2 = relu(Agg(x1@W2)+b2); out = [x1,x2]@linW + linb
// Agg(h)[i] = dinv[i]^2*h[i] + sum_{e: dst=i} dinv[src]*dinv[i]*h[src]
// CSR by dst (counting sort) -> per-node wave gather-reduce. n=50000, D=128, E=800000.
// GEMM: W-tile in LDS with XOR-swizzled float4 slots (p = s ^ (s>>3)).
// Read side applies the SAME forward map (p0 = p(2cg), second word = p0^1),
// so data comes back in logical order — no epilogue permutation (R5 bug).

#define D128 128
#define AS_STRIDE 132  // 128 + 4 pad for A tile rows

// ---------- degree count ----------
__global__ void k_count(const int* __restrict__ dst, int* __restrict__ indeg, int E) {
    int e = blockIdx.x * 256 + threadIdx.x;
    if (e < E) atomicAdd(&indeg[dst[e]], 1);
}

// ---------- scan (exclusive) over indeg -> row_ptr ; fused dinv ----------
__global__ void k_scan1(const int* __restrict__ indeg, int* __restrict__ row_ptr,
                        int* __restrict__ bsum, float* __restrict__ dinv, int n) {
    __shared__ int tmp[256];
    int i = blockIdx.x * 256 + threadIdx.x;
    int v = (i < n) ? indeg[i] : 0;
    if (i < n) dinv[i] = rsqrtf((float)(v + 1));  // +1 self loop
    tmp[threadIdx.x] = v;
    __syncthreads();
    for (int off = 1; off < 256; off <<= 1) {
        int t = (threadIdx.x >= off) ? tmp[threadIdx.x - off] : 0;
        __syncthreads();
        tmp[threadIdx.x] += t;
        __syncthreads();
    }
    if (i < n) row_ptr[i] = tmp[threadIdx.x] - v;
    if (threadIdx.x == 255) bsum[blockIdx.x] = tmp[255];
}

__global__ void k_scan2(int* __restrict__ bsum, int nb) {  // one block, nb<=256
    __shared__ int tmp[256];
    int v = (threadIdx.x < nb) ? bsum[threadIdx.x] : 0;
    tmp[threadIdx.x] = v;
    __syncthreads();
    for (int off = 1; off < 256; off <<= 1) {
        int t = (threadIdx.x >= off) ? tmp[threadIdx.x - off] : 0;
        __syncthreads();
        tmp[threadIdx.x] += t;
        __syncthreads();
    }
    if (threadIdx.x < nb) bsum[threadIdx.x] = tmp[threadIdx.x] - v;
}

__global__ void k_scan3(int* __restrict__ row_ptr, const int* __restrict__ bsum,
                        int* __restrict__ cursor, int n, int E) {
    int i = blockIdx.x * 256 + threadIdx.x;
    if (i < n) {
        int r = row_ptr[i] + bsum[blockIdx.x];
        row_ptr[i] = r;
        cursor[i] = r;
    }
    if (blockIdx.x == 0 && threadIdx.x == 0) row_ptr[n] = E;
}

// ---------- CSR fill: packed (src_bits, norm) ----------
__global__ void k_fill(const int* __restrict__ src, const int* __restrict__ dst,
                       const float* __restrict__ dinv, int* __restrict__ cursor,
                       float2* __restrict__ csr, int E) {
    int e = blockIdx.x * 256 + threadIdx.x;
    if (e >= E) return;
    int s = src[e], d = dst[e];
    int pos = atomicAdd(&cursor[d], 1);
    csr[pos] = make_float2(__int_as_float(s), dinv[s] * dinv[d]);
}

// ---------- fused aggregate + bias + relu ----------
// 1 wave per node, float2 per lane; 8 gathers in flight.
__global__ __launch_bounds__(256) void k_agg_csr(
    const float* __restrict__ h, const int* __restrict__ row_ptr,
    const float2* __restrict__ csr, const float* __restrict__ dinv,
    const float* __restrict__ bias, float* __restrict__ o, int n)
{
    int node = blockIdx.x * 4 + (threadIdx.x >> 6);
    int lane = threadIdx.x & 63;
    if (node >= n) return;
    const float2* h2 = (const float2*)h;
    float dv = dinv[node];
    float2 hv = h2[node * 64 + lane];
    float ax = dv * dv * hv.x, ay = dv * dv * hv.y;
    int j = row_ptr[node], end = row_ptr[node + 1];
    for (; j + 7 < end; j += 8) {
        float2 c0 = csr[j+0], c1 = csr[j+1], c2 = csr[j+2], c3 = csr[j+3];
        float2 c4 = csr[j+4], c5 = csr[j+5], c6 = csr[j+6], c7 = csr[j+7];
        float2 v0 = h2[__float_as_int(c0.x) * 64 + lane];
        float2 v1 = h2[__float_as_int(c1.x) * 64 + lane];
        float2 v2 = h2[__float_as_int(c2.x) * 64 + lane];
        float2 v3 = h2[__float_as_int(c3.x) * 64 + lane];
        float2 v4 = h2[__float_as_int(c4.x) * 64 + lane];
        float2 v5 = h2[__float_as_int(c5.x) * 64 + lane];
        float2 v6 = h2[__float_as_int(c6.x) * 64 + lane];
        float2 v7 = h2[__float_as_int(c7.x) * 64 + lane];
        ax += c0.y*v0.x + c1.y*v1.x + c2.y*v2.x + c3.y*v3.x
            + c4.y*v4.x + c5.y*v5.x + c6.y*v6.x + c7.y*v7.x;
        ay += c0.y*v0.y + c1.y*v1.y + c2.y*v2.y + c3.y*v3.y
            + c4.y*v4.y + c5.y*v5.y + c6.y*v6.y + c7.y*v7.y;
    }
    for (; j + 3 < end; j += 4) {
        float2 c0 = csr[j+0], c1 = csr[j+1], c2 = csr[j+2], c3 = csr[j+3];
        float2 v0 = h2[__float_as_int(c0.x) * 64 + lane];
        float2 v1 = h2[__float_as_int(c1.x) * 64 + lane];
        float2 v2 = h2[__float_as_int(c2.x) * 64 + lane];
        float2 v3 = h2[__float_as_int(c3.x) * 64 + lane];
        ax += c0.y*v0.x + c1.y*v1.x + c2.y*v2.x + c3.y*v3.x;
        ay += c0.y*v0.y + c1.y*v1.y + c2.y*v2.y + c3.y*v3.y;
    }
    for (; j < end; ++j) {
        float2 c = csr[j];
        float2 v = h2[__float_as_int(c.x) * 64 + lane];
        ax += c.y * v.x;
        ay += c.y * v.y;
    }
    float2 bv = ((const float2*)bias)[lane];
    float2 ov = {fmaxf(ax + bv.x, 0.f), fmaxf(ay + bv.y, 0.f)};
    ((float2*)o)[node * 64 + lane] = ov;
}

// Stage 64 rows x 128 cols of W into Wc with XOR-swizzled float4 slots.
// physical slot p = s ^ (s>>3)  (bijective within each 8-slot group).
__device__ __forceinline__ void stage_W64(const float* __restrict__ Wsrc, float* Wc, int tid) {
    const float4* W4 = (const float4*)Wsrc;
#pragma unroll
    for (int it = 0; it < 8; ++it) {
        int f = it * 256 + tid;       // float4 idx in 64x32 slot grid
        int r = f >> 5, s = f & 31;
        int p = s ^ (s >> 3);
        *(float4*)&Wc[r * D128 + p * 4] = W4[f];
    }
}

// ---------- dense GEMM: C[32 x 128] = A@W, K=128; thread = 2 rows x 8 cols ----------
__global__ __launch_bounds__(256) void k_gemm(
    const float* __restrict__ A, const float* __restrict__ W,
    float* __restrict__ C, int n)
{
    __shared__ float Wc[64 * D128];       // 32 KB (K-chunk, swizzled slots)
    __shared__ float As[32 * AS_STRIDE];  // 16.5 KB
    int tid = threadIdx.x;
    int row0 = blockIdx.x * 32;

    {   // stage A tile (zero-fill OOB rows)
        const float4* A4 = (const float4*)(A + (size_t)row0 * D128);
#pragma unroll
        for (int it = 0; it < 4; ++it) {
            int f = it * 256 + tid;
            int r = f >> 5, c4 = f & 31;
            float4 v = {0.f, 0.f, 0.f, 0.f};
            if (row0 + r < n) v = A4[f];
            *(float4*)&As[r * AS_STRIDE + c4 * 4] = v;
        }
    }

    int cg = tid & 15;                 // cols cg*8 .. cg*8+7
    int rg = tid >> 4;                 // rows rg*2, rg*2+1
    int p0 = (2 * cg) ^ (cg >> 2);     // forward map of logical slot 2cg
    float4 acc[2][2] = {{{0,0,0,0},{0,0,0,0}},{{0,0,0,0},{0,0,0,0}}};
    const float* a0p = &As[(rg * 2) * AS_STRIDE];
    const float* a1p = &As[(rg * 2 + 1) * AS_STRIDE];

    for (int kb = 0; kb < 2; ++kb) {
        if (kb) __syncthreads();
        stage_W64(W + kb * 64 * D128, Wc, tid);
        __syncthreads();

#pragma unroll 4
        for (int k = 0; k < 64; ++k) {
            float4 w0 = *(const float4*)&Wc[k * D128 + p0 * 4];        // cols cg*8..+3
            float4 w1 = *(const float4*)&Wc[k * D128 + (p0 ^ 1) * 4];  // cols cg*8+4..+7
            float a0 = a0p[kb * 64 + k];
            float a1 = a1p[kb * 64 + k];
            acc[0][0].x += a0*w0.x; acc[0][0].y += a0*w0.y; acc[0][0].z += a0*w0.z; acc[0][0].w += a0*w0.w;
            acc[0][1].x += a0*w1.x; acc[0][1].y += a0*w1.y; acc[0][1].z += a0*w1.z; acc[0][1].w += a0*w1.w;
            acc[1][0].x += a1*w0.x; acc[1][0].y += a1*w0.y; acc[1][0].z += a1*w0.z; acc[1][0].w += a1*w0.w;
            acc[1][1].x += a1*w1.x; acc[1][1].y += a1*w1.y; acc[1][1].z += a1*w1.z; acc[1][1].w += a1*w1.w;
        }
    }

#pragma unroll
    for (int r = 0; r < 2; ++r) {
        int row = row0 + rg * 2 + r;
        if (row < n) {
            float4* Cp = (float4*)&C[(size_t)row * D128 + cg * 8];
            Cp[0] = acc[r][0];
            Cp[1] = acc[r][1];
        }
    }
}

// ---------- final: out = [x1,x2] @ linW + linb  (K=256 in 4 chunks of 64) ----------
__global__ __launch_bounds__(256) void k_gemm_cat(
    const float* __restrict__ A0, const float* __restrict__ A1,
    const float* __restrict__ W, const float* __restrict__ bias,
    float* __restrict__ C, int n)
{
    __shared__ float Wc[64 * D128];       // 32 KB
    __shared__ float As[32 * AS_STRIDE];  // 16.5 KB
    int tid = threadIdx.x;
    int row0 = blockIdx.x * 32;

    int cg = tid & 15;
    int rg = tid >> 4;
    int p0 = (2 * cg) ^ (cg >> 2);
    float4 acc[2][2] = {{{0,0,0,0},{0,0,0,0}},{{0,0,0,0},{0,0,0,0}}};

    for (int ch = 0; ch < 4; ++ch) {
        if (ch) __syncthreads();          // prior compute done before overwrite
        if (ch == 0 || ch == 2) {         // (re)stage A half
            const float* Asrc = (ch == 0) ? A0 : A1;
            const float4* A4 = (const float4*)(Asrc + (size_t)row0 * D128);
#pragma unroll
            for (int it = 0; it < 4; ++it) {
                int f = it * 256 + tid;
                int r = f >> 5, c4 = f & 31;
                float4 v = {0.f, 0.f, 0.f, 0.f};
                if (row0 + r < n) v = A4[f];
                *(float4*)&As[r * AS_STRIDE + c4 * 4] = v;
            }
        }
        stage_W64(W + ch * 64 * D128, Wc, tid);
        __syncthreads();

        const float* a0p = &As[(rg * 2) * AS_STRIDE] + (ch & 1) * 64;
        const float* a1p = &As[(rg * 2 + 1) * AS_STRIDE] + (ch & 1) * 64;
#pragma unroll 4
        for (int k = 0; k < 64; ++k) {
            float4 w0 = *(const float4*)&Wc[k * D128 + p0 * 4];
            float4 w1 = *(const float4*)&Wc[k * D128 + (p0 ^ 1) * 4];
            float a0 = a0p[k];
            float a1 = a1p[k];
            acc[0][0].x += a0*w0.x; acc[0][0].y += a0*w0.y; acc[0][0].z += a0*w0.z; acc[0][0].w += a0*w0.w;
            acc[0][1].x += a0*w1.x; acc[0][1].y += a0*w1.y; acc[0][1].z += a0*w1.z; acc[0][1].w += a0*w1.w;
            acc[1][0].x += a1*w0.x; acc[1][0].y += a1*w0.y; acc[1][0].z += a1*w0.z; acc[1][0].w += a1*w0.w;
            acc[1][1].x += a1*w1.x; acc[1][1].y += a1*w1.y; acc[1][1].z += a1*w1.z; acc[1][1].w += a1*w1.w;
        }
    }

    float4 bv0 = ((const float4*)bias)[cg * 2];
    float4 bv1 = ((const float4*)bias)[cg * 2 + 1];
#pragma unroll
    for (int r = 0; r < 2; ++r) {
        int row = row0 + rg * 2 + r;
        if (row < n) {
            float4* Cp = (float4*)&C[(size_t)row * D128 + cg * 8];
            float4 v0 = acc[r][0], v1 = acc[r][1];
            v0.x += bv0.x; v0.y += bv0.y; v0.z += bv0.z; v0.w += bv0.w;
            v1.x += bv1.x; v1.y += bv1.y; v1.z += bv1.z; v1.w += bv1.w;
            Cp[0] = v0;
            Cp[1] = v1;
        }
    }
}

extern "C" void kernel_launch(void* const* d_in, const int* in_sizes, int n_in,
                              void* d_out, int out_size, void* d_ws, size_t ws_size,
                              hipStream_t stream) {
    const float* x    = (const float*)d_in[0];
    const int*   ei   = (const int*)d_in[1];
    const float* W1   = (const float*)d_in[2];
    const float* b1   = (const float*)d_in[3];
    const float* W2   = (const float*)d_in[4];
    const float* b2   = (const float*)d_in[5];
    const float* linW = (const float*)d_in[6];
    const float* linb = (const float*)d_in[7];

    int n = in_sizes[0] / D128;
    int E = in_sizes[1] / 2;
    const int* src = ei;
    const int* dst = ei + E;

    float* out = (float*)d_out;
    float* ws  = (float*)d_ws;

    // ws layout (floats): csr[2E] | indeg[n] | dinv[n] | row_ptr[n+1] | bsum[256]
    //                     | cursor[n] | (align) | x1[n*128] | x2[n*128]
    size_t o = 0;
    float2* csr   = (float2*)(ws + o);  o += 2 * (size_t)E;
    int*   indeg  = (int*)(ws + o);     o += n;
    float* dinv   = ws + o;             o += n;
    int*   row_ptr= (int*)(ws + o);     o += n + 1;
    int*   bsum   = (int*)(ws + o);     o += 256;
    int*   cursor = (int*)(ws + o);     o += n;
    o = (o + 3) & ~(size_t)3;
    float* x1     = ws + o;             o += (size_t)n * D128;
    float* x2     = ws + o;
    float* h      = out;  // reuse output buffer as GEMM scratch

    int gn = (n + 255) / 256;
    int gE = (E + 255) / 256;
    int gemmBlocks = (n + 31) / 32;
    int aggBlocks  = (n + 3) / 4;

    // CSR build
    hipMemsetAsync(indeg, 0, (size_t)n * sizeof(int), stream);
    k_count<<<gE, 256, 0, stream>>>(dst, indeg, E);
    k_scan1<<<gn, 256, 0, stream>>>(indeg, row_ptr, bsum, dinv, n);
    k_scan2<<<1, 256, 0, stream>>>(bsum, gn);
    k_scan3<<<gn, 256, 0, stream>>>(row_ptr, bsum, cursor, n, E);
    k_fill<<<gE, 256, 0, stream>>>(src, dst, dinv, cursor, csr, E);

    // layer 1
    k_gemm<<<gemmBlocks, 256, 0, stream>>>(x, W1, h, n);
    k_agg_csr<<<aggBlocks, 256, 0, stream>>>(h, row_ptr, csr, dinv, b1, x1, n);

    // layer 2
    k_gemm<<<gemmBlocks, 256, 0, stream>>>(x1, W2, h, n);
    k_agg_csr<<<aggBlocks, 256, 0, stream>>>(h, row_ptr, csr, dinv, b2, x2, n);

    // final
    k_gemm_cat<<<gemmBlocks, 256, 0, stream>>>(x1, x2, linW, linb, out, n);
}